// Round 5
// baseline (215.799 us; speedup 1.0000x reference)
//
#include <hip/hip_runtime.h>
#include <math.h>

// Problem constants (from reference setup_inputs)
#define BB 512
#define HH 512
#define RR 2048
#define CC 64
#define OUTD 202          // 3*64 + 2*3 + 4
// params workspace layout per batch (floats)
#define PSTRIDE 208
#define K_OFF 0
#define E_OFF 64
#define A_OFF 128
#define S_OFF 192         // 7 softmaxed shift weights
#define COMBO_OFF 199     // beta / k_n
#define G_OFF 200
#define GAMMA_OFF 201

#define NCHUNK 2
#define CB (BB / NCHUNK)   // 256 batches per chunk = 128 MB of memory[]

typedef float f32x4 __attribute__((ext_vector_type(4)));

__device__ __forceinline__ float softplusf_(float x) {
    return (x > 20.f) ? x : log1pf(expf(x));
}
__device__ __forceinline__ float sigmoidf_(float x) {
    return 1.f / (1.f + expf(-x));
}

// ---------------------------------------------------------------------------
// Kernel A: z = h @ fc_w^T + fc_b, activations -> packed params in ws.
// ---------------------------------------------------------------------------
__global__ __launch_bounds__(256) void params_kernel(
    const float* __restrict__ h, const float* __restrict__ fc_w,
    const float* __restrict__ fc_b, float* __restrict__ pw)
{
    __shared__ float h_sh[8][HH];
    __shared__ float z_sh[8][204];
    const int tid = threadIdx.x;
    const int b0 = blockIdx.x * 8;

    for (int idx = tid; idx < 8 * HH; idx += 256) {
        int j = idx >> 9, i = idx & 511;
        h_sh[j][i] = h[(size_t)(b0 + j) * HH + i];
    }
    __syncthreads();

    if (tid < OUTD) {
        float acc[8];
        #pragma unroll
        for (int j = 0; j < 8; ++j) acc[j] = 0.f;
        const float4* wr4 = (const float4*)(fc_w + (size_t)tid * HH);
        for (int i4 = 0; i4 < HH / 4; ++i4) {
            float4 wv = wr4[i4];
            int i = i4 * 4;
            #pragma unroll
            for (int j = 0; j < 8; ++j) {
                acc[j] = fmaf(wv.x, h_sh[j][i + 0], acc[j]);
                acc[j] = fmaf(wv.y, h_sh[j][i + 1], acc[j]);
                acc[j] = fmaf(wv.z, h_sh[j][i + 2], acc[j]);
                acc[j] = fmaf(wv.w, h_sh[j][i + 3], acc[j]);
            }
        }
        float bias = fc_b[tid];
        #pragma unroll
        for (int j = 0; j < 8; ++j) z_sh[j][tid] = acc[j] + bias;
    }
    __syncthreads();

    for (int idx = tid; idx < 8 * OUTD; idx += 256) {
        int j = idx / OUTD;
        int t = idx - j * OUTD;
        float z = z_sh[j][t];
        float* p = pw + (size_t)(b0 + j) * PSTRIDE;
        if (t < 64)            p[K_OFF + t] = tanhf(z);
        else if (t == 65)      p[G_OFF] = sigmoidf_(z);
        else if (t == 73)      p[GAMMA_OFF] = softplusf_(z) + 1.f;
        else if (t >= 74 && t < 138) p[E_OFF + (t - 74)] = sigmoidf_(z);
        else if (t >= 138)     p[A_OFF + (t - 138)] = tanhf(z);
    }
    __syncthreads();

    if (tid < 8) {
        int j = tid;
        float* p = pw + (size_t)(b0 + j) * PSTRIDE;
        float ss = 0.f;
        for (int c = 0; c < 64; ++c) {
            float kv = tanhf(z_sh[j][c]);
            ss += kv * kv;
        }
        float kn = fmaxf(sqrtf(ss), 1e-8f);
        float beta = softplusf_(z_sh[j][64]);
        p[COMBO_OFF] = beta / kn;
        float mx = -1e30f;
        for (int q = 0; q < 7; ++q) mx = fmaxf(mx, z_sh[j][66 + q]);
        float ev[7], se = 0.f;
        for (int q = 0; q < 7; ++q) { ev[q] = expf(z_sh[j][66 + q] - mx); se += ev[q]; }
        float inv = 1.f / se;
        for (int q = 0; q < 7; ++q) p[S_OFF + q] = ev[q] * inv;
    }
}

// ---------------------------------------------------------------------------
// Kernel S: sc[b][r] = exp(combo * (k . m_r) / max(||m_r||, eps)) for one
// batch-chunk. Allocating loads: the chunk (128 MB) parks in L3 for the
// update kernel's re-read. Max-free softmax is exact (|arg| <= beta).
// ---------------------------------------------------------------------------
__global__ __launch_bounds__(256) void score_kernel(
    const float* __restrict__ memory, const float* __restrict__ pw,
    float* __restrict__ sc, int bofs)
{
    const int tid = threadIdx.x;
    const int b = bofs + (blockIdx.x >> 2);
    const int rbase = (blockIdx.x & 3) * 512;
    const int lane16 = tid & 15;
    const int rgrp = tid >> 4;            // 0..15
    const float* p = pw + (size_t)b * PSTRIDE;
    const float4 k4 = *(const float4*)(p + K_OFF + lane16 * 4);
    const float combo = p[COMBO_OFF];
    const float* memb = memory + (size_t)b * RR * CC;

    #pragma unroll 8
    for (int i = 0; i < 32; ++i) {
        int r = rbase + i * 16 + rgrp;
        float4 m4 = *(const float4*)(memb + (size_t)r * CC + lane16 * 4);
        float num = m4.x * k4.x + m4.y * k4.y + m4.z * k4.z + m4.w * k4.w;
        float ssq = m4.x * m4.x + m4.y * m4.y + m4.z * m4.z + m4.w * m4.w;
        #pragma unroll
        for (int m = 1; m < 16; m <<= 1) {
            num += __shfl_xor(num, m, 64);
            ssq += __shfl_xor(ssq, m, 64);
        }
        if (lane16 == 0) {
            float mn = fmaxf(sqrtf(ssq), 1e-8f);
            sc[(size_t)b * RR + r] = __expf(combo * num / mn);
        }
    }
}

// ---------------------------------------------------------------------------
// Kernel W: per-batch softmax-sum -> gate -> 7-tap circular conv -> pow ->
// normalize -> out_w, for one chunk. 256 threads/block, rows in LDS.
// ---------------------------------------------------------------------------
__device__ __forceinline__ float block_reduce_sum4(float v, float* red) {
    #pragma unroll
    for (int m = 1; m < 64; m <<= 1) v += __shfl_xor(v, m, 64);
    int wid = threadIdx.x >> 6;
    if ((threadIdx.x & 63) == 0) red[wid] = v;
    __syncthreads();
    float x = red[0] + red[1] + red[2] + red[3];
    __syncthreads();
    return x;
}

__global__ __launch_bounds__(256) void weight_kernel(
    const float* __restrict__ sc, const float* __restrict__ prev_w,
    const float* __restrict__ pw, float* __restrict__ out_w, int bofs)
{
    __shared__ float buf[RR];
    __shared__ float wg[RR];
    __shared__ float red[4];
    const int b = bofs + blockIdx.x;
    const int tid = threadIdx.x;
    const float* p = pw + (size_t)b * PSTRIDE;
    const float g = p[G_OFF];
    const float gamma = p[GAMMA_OFF];
    const float s0 = p[S_OFF + 0], s1 = p[S_OFF + 1], s2 = p[S_OFF + 2],
                s3 = p[S_OFF + 3], s4 = p[S_OFF + 4], s5 = p[S_OFF + 5],
                s6 = p[S_OFF + 6];

    float ls = 0.f;
    for (int r = tid; r < RR; r += 256) {
        float ev = sc[(size_t)b * RR + r];
        buf[r] = ev;
        ls += ev;
    }
    const float se = block_reduce_sum4(ls, red);
    const float invse = 1.f / se;

    for (int r = tid; r < RR; r += 256) {
        wg[r] = g * (buf[r] * invse) + (1.f - g) * prev_w[(size_t)b * RR + r];
    }
    __syncthreads();

    float lp = 0.f;
    for (int r = tid; r < RR; r += 256) {
        float acc = s0 * wg[(r - 3) & (RR - 1)]
                  + s1 * wg[(r - 2) & (RR - 1)]
                  + s2 * wg[(r - 1) & (RR - 1)]
                  + s3 * wg[r]
                  + s4 * wg[(r + 1) & (RR - 1)]
                  + s5 * wg[(r + 2) & (RR - 1)]
                  + s6 * wg[(r + 3) & (RR - 1)];
        float wp = __powf(acc, gamma);
        buf[r] = wp;
        lp += wp;
    }
    const float ps = block_reduce_sum4(lp, red);
    const float invp = 1.f / (ps + 1e-16f);

    for (int r = tid; r < RR; r += 256) {
        out_w[(size_t)b * RR + r] = buf[r] * invp;
    }
}

// ---------------------------------------------------------------------------
// Kernel U: new_mem = mem*(1 - w*e) + w*a for one chunk. The chunk's memory
// lines were just allocated in L3 by score_kernel: NT loads hit them (and
// mark them evict-early — last use), NT stores stream out without
// allocating, so they don't evict the next chunk's working set.
// ---------------------------------------------------------------------------
__global__ __launch_bounds__(256) void update_kernel(
    const float* __restrict__ memory, const float* __restrict__ w,
    const float* __restrict__ pw, float* __restrict__ out_mem, int bofs)
{
    const int b = bofs + ((int)blockIdx.x >> 2);
    const int rbase = ((int)blockIdx.x & 3) * 512;
    const int tid = threadIdx.x;
    const int lane16 = tid & 15;
    const int rgrp = tid >> 4;            // 0..15
    const float* p = pw + (size_t)b * PSTRIDE;
    const f32x4 e4 = *(const f32x4*)(p + E_OFF + lane16 * 4);
    const f32x4 a4 = *(const f32x4*)(p + A_OFF + lane16 * 4);
    const float* memb = memory + (size_t)b * RR * CC;
    float* omb = out_mem + (size_t)b * RR * CC;
    const float* wb = w + (size_t)b * RR;

    #pragma unroll 8
    for (int i = 0; i < 32; ++i) {
        int r = rbase + i * 16 + rgrp;
        float wv = wb[r];
        f32x4 m4 = __builtin_nontemporal_load(
            (const f32x4*)(memb + (size_t)r * CC) + lane16);
        f32x4 o;
        o.x = m4.x * (1.f - wv * e4.x) + wv * a4.x;
        o.y = m4.y * (1.f - wv * e4.y) + wv * a4.y;
        o.z = m4.z * (1.f - wv * e4.z) + wv * a4.z;
        o.w = m4.w * (1.f - wv * e4.w) + wv * a4.w;
        __builtin_nontemporal_store(o, (f32x4*)(omb + (size_t)r * CC) + lane16);
    }
}

extern "C" void kernel_launch(void* const* d_in, const int* in_sizes, int n_in,
                              void* d_out, int out_size, void* d_ws, size_t ws_size,
                              hipStream_t stream) {
    const float* h      = (const float*)d_in[0];
    const float* prev_w = (const float*)d_in[1];
    const float* memory = (const float*)d_in[2];
    const float* fc_w   = (const float*)d_in[3];
    const float* fc_b   = (const float*)d_in[4];

    float* pw      = (float*)d_ws;              // 512*208*4 = 416 KB
    float* out_w   = (float*)d_out;             // B*R
    float* out_mem = out_w + (size_t)BB * RR;   // B*R*C

    const size_t pw_bytes = (size_t)BB * PSTRIDE * sizeof(float);
    const size_t sc_bytes = (size_t)BB * RR * sizeof(float);

    params_kernel<<<64, 256, 0, stream>>>(h, fc_w, fc_b, pw);

    if (ws_size >= pw_bytes + sc_bytes) {
        // sc in d_ws; chunk batches so update's re-read of memory hits L3
        float* sc = pw + (size_t)BB * PSTRIDE;
        for (int c = 0; c < NCHUNK; ++c) {
            int b0 = c * CB;
            score_kernel<<<CB * 4, 256, 0, stream>>>(memory, pw, sc, b0);
            weight_kernel<<<CB, 256, 0, stream>>>(sc, prev_w, pw, out_w, b0);
            update_kernel<<<CB * 4, 256, 0, stream>>>(memory, out_w, pw,
                                                      out_mem, b0);
        }
    } else {
        // fallback (small ws): sc aliased onto out_mem, non-chunked; the
        // kernel boundary orders sc reads before update's overwrites.
        float* sc = out_mem;
        score_kernel<<<BB * 4, 256, 0, stream>>>(memory, pw, sc, 0);
        weight_kernel<<<BB, 256, 0, stream>>>(sc, prev_w, pw, out_w, 0);
        update_kernel<<<BB * 4, 256, 0, stream>>>(memory, out_w, pw, out_mem, 0);
    }
}

// Round 6
// 206.625 us; speedup vs baseline: 1.0444x; 1.0444x over previous
//
#include <hip/hip_runtime.h>
#include <math.h>

// Problem constants (from reference setup_inputs)
#define BB 512
#define HH 512
#define RR 2048
#define CC 64
#define OUTD 202          // 3*64 + 2*3 + 4
// params workspace layout per batch (floats)
#define PSTRIDE 208
#define K_OFF 0
#define E_OFF 64
#define A_OFF 128
#define S_OFF 192         // 7 softmaxed shift weights
#define COMBO_OFF 199     // beta / k_n
#define G_OFF 200
#define GAMMA_OFF 201

typedef float f32x4 __attribute__((ext_vector_type(4)));

__device__ __forceinline__ float softplusf_(float x) {
    return (x > 20.f) ? x : log1pf(expf(x));
}
__device__ __forceinline__ float sigmoidf_(float x) {
    return 1.f / (1.f + expf(-x));
}

// ---------------------------------------------------------------------------
// Kernel A: z = h @ fc_w^T + fc_b, activations -> packed params in ws.
// ---------------------------------------------------------------------------
__global__ __launch_bounds__(256) void params_kernel(
    const float* __restrict__ h, const float* __restrict__ fc_w,
    const float* __restrict__ fc_b, float* __restrict__ pw)
{
    __shared__ float h_sh[8][HH];
    __shared__ float z_sh[8][204];
    const int tid = threadIdx.x;
    const int b0 = blockIdx.x * 8;

    for (int idx = tid; idx < 8 * HH; idx += 256) {
        int j = idx >> 9, i = idx & 511;
        h_sh[j][i] = h[(size_t)(b0 + j) * HH + i];
    }
    __syncthreads();

    if (tid < OUTD) {
        float acc[8];
        #pragma unroll
        for (int j = 0; j < 8; ++j) acc[j] = 0.f;
        const float4* wr4 = (const float4*)(fc_w + (size_t)tid * HH);
        for (int i4 = 0; i4 < HH / 4; ++i4) {
            float4 wv = wr4[i4];
            int i = i4 * 4;
            #pragma unroll
            for (int j = 0; j < 8; ++j) {
                acc[j] = fmaf(wv.x, h_sh[j][i + 0], acc[j]);
                acc[j] = fmaf(wv.y, h_sh[j][i + 1], acc[j]);
                acc[j] = fmaf(wv.z, h_sh[j][i + 2], acc[j]);
                acc[j] = fmaf(wv.w, h_sh[j][i + 3], acc[j]);
            }
        }
        float bias = fc_b[tid];
        #pragma unroll
        for (int j = 0; j < 8; ++j) z_sh[j][tid] = acc[j] + bias;
    }
    __syncthreads();

    for (int idx = tid; idx < 8 * OUTD; idx += 256) {
        int j = idx / OUTD;
        int t = idx - j * OUTD;
        float z = z_sh[j][t];
        float* p = pw + (size_t)(b0 + j) * PSTRIDE;
        if (t < 64)            p[K_OFF + t] = tanhf(z);
        else if (t == 65)      p[G_OFF] = sigmoidf_(z);
        else if (t == 73)      p[GAMMA_OFF] = softplusf_(z) + 1.f;
        else if (t >= 74 && t < 138) p[E_OFF + (t - 74)] = sigmoidf_(z);
        else if (t >= 138)     p[A_OFF + (t - 138)] = tanhf(z);
    }
    __syncthreads();

    if (tid < 8) {
        int j = tid;
        float* p = pw + (size_t)(b0 + j) * PSTRIDE;
        float ss = 0.f;
        for (int c = 0; c < 64; ++c) {
            float kv = tanhf(z_sh[j][c]);
            ss += kv * kv;
        }
        float kn = fmaxf(sqrtf(ss), 1e-8f);
        float beta = softplusf_(z_sh[j][64]);
        p[COMBO_OFF] = beta / kn;
        float mx = -1e30f;
        for (int q = 0; q < 7; ++q) mx = fmaxf(mx, z_sh[j][66 + q]);
        float ev[7], se = 0.f;
        for (int q = 0; q < 7; ++q) { ev[q] = expf(z_sh[j][66 + q] - mx); se += ev[q]; }
        float inv = 1.f / se;
        for (int q = 0; q < 7; ++q) p[S_OFF + q] = ev[q] * inv;
    }
}

// ---------------------------------------------------------------------------
// reduce helper: 256-thread block sum, fixed order (deterministic)
// ---------------------------------------------------------------------------
__device__ __forceinline__ float block_reduce_sum4(float v, float* red) {
    #pragma unroll
    for (int m = 1; m < 64; m <<= 1) v += __shfl_xor(v, m, 64);
    int wid = threadIdx.x >> 6;
    if ((threadIdx.x & 63) == 0) red[wid] = v;
    __syncthreads();
    float x = red[0] + red[1] + red[2] + red[3];
    __syncthreads();
    return x;
}

// ---------------------------------------------------------------------------
// Kernel S: sc[b][r] = exp(combo * cos_r); also per-(b,quarter) exp-sum
// partial -> esum (fixed-order reduce, deterministic). Allocating loads so
// memory parks in L2/L3 for update's re-read. Max-free softmax (|arg|<=beta).
// ---------------------------------------------------------------------------
__global__ __launch_bounds__(256) void score_kernel(
    const float* __restrict__ memory, const float* __restrict__ pw,
    float* __restrict__ sc, float* __restrict__ esum)
{
    __shared__ float red[4];
    const int tid = threadIdx.x;
    const int b = blockIdx.x >> 2;
    const int rbase = (blockIdx.x & 3) * 512;
    const int lane16 = tid & 15;
    const int rgrp = tid >> 4;            // 0..15
    const float* p = pw + (size_t)b * PSTRIDE;
    const float4 k4 = *(const float4*)(p + K_OFF + lane16 * 4);
    const float combo = p[COMBO_OFF];
    const float* memb = memory + (size_t)b * RR * CC;

    float lsum = 0.f;
    #pragma unroll 8
    for (int i = 0; i < 32; ++i) {
        int r = rbase + i * 16 + rgrp;
        float4 m4 = *(const float4*)(memb + (size_t)r * CC + lane16 * 4);
        float num = m4.x * k4.x + m4.y * k4.y + m4.z * k4.z + m4.w * k4.w;
        float ssq = m4.x * m4.x + m4.y * m4.y + m4.z * m4.z + m4.w * m4.w;
        #pragma unroll
        for (int m = 1; m < 16; m <<= 1) {
            num += __shfl_xor(num, m, 64);
            ssq += __shfl_xor(ssq, m, 64);
        }
        if (lane16 == 0) {
            float mn = fmaxf(sqrtf(ssq), 1e-8f);
            float ev = __expf(combo * num / mn);
            sc[(size_t)b * RR + r] = ev;
            lsum += ev;
        }
    }
    float bs = block_reduce_sum4(lsum, red);
    if (tid == 0) esum[blockIdx.x] = bs;
}

// ---------------------------------------------------------------------------
// Kernel C: quarter-batch gate + 7-tap circular conv + pow.
// wg is local given invse, so only a +-3 halo is recomputed per block.
// Writes w_p to ws and per-(b,quarter) pow-sum partials.
// ---------------------------------------------------------------------------
__global__ __launch_bounds__(256) void wconv_kernel(
    const float* __restrict__ sc, const float* __restrict__ prev_w,
    const float* __restrict__ pw, const float* __restrict__ esum,
    float* __restrict__ wp, float* __restrict__ psum)
{
    __shared__ float wgs[518];
    __shared__ float red[4];
    const int tid = threadIdx.x;
    const int b = blockIdx.x >> 2;
    const int r0 = (blockIdx.x & 3) * 512;
    const float* p = pw + (size_t)b * PSTRIDE;
    const float g = p[G_OFF];
    const float gamma = p[GAMMA_OFF];
    const float s0 = p[S_OFF + 0], s1 = p[S_OFF + 1], s2 = p[S_OFF + 2],
                s3 = p[S_OFF + 3], s4 = p[S_OFF + 4], s5 = p[S_OFF + 5],
                s6 = p[S_OFF + 6];
    const float* eb = esum + (size_t)b * 4;
    const float invse = 1.f / (eb[0] + eb[1] + eb[2] + eb[3]);
    const float gi = g * invse, omg = 1.f - g;

    // gate for rows r0-3 .. r0+514 (circular)
    for (int idx = tid; idx < 518; idx += 256) {
        int r = (r0 - 3 + idx) & (RR - 1);
        wgs[idx] = gi * sc[(size_t)b * RR + r]
                 + omg * prev_w[(size_t)b * RR + r];
    }
    __syncthreads();

    float lp = 0.f;
    #pragma unroll
    for (int t2 = 0; t2 < 2; ++t2) {
        int idx = t2 * 256 + tid;
        float acc = s0 * wgs[idx]     + s1 * wgs[idx + 1]
                  + s2 * wgs[idx + 2] + s3 * wgs[idx + 3]
                  + s4 * wgs[idx + 4] + s5 * wgs[idx + 5]
                  + s6 * wgs[idx + 6];
        float v = __powf(acc, gamma);
        wp[(size_t)b * RR + r0 + idx] = v;
        lp += v;
    }
    float bs = block_reduce_sum4(lp, red);
    if (tid == 0) psum[blockIdx.x] = bs;
}

// ---------------------------------------------------------------------------
// Kernel U: normalize w while streaming the memory update.
// Reverse block order (read the L3-MRU end first). Normal loads for memory
// (hit L3 lines score allocated), NT stores for the out stream.
// ---------------------------------------------------------------------------
__global__ __launch_bounds__(256) void update_kernel(
    const float* __restrict__ memory, const float* __restrict__ wp,
    const float* __restrict__ psum, const float* __restrict__ pw,
    float* __restrict__ out_w, float* __restrict__ out_mem)
{
    const int bid = (int)gridDim.x - 1 - (int)blockIdx.x;
    const int b = bid >> 2;
    const int rbase = (bid & 3) * 512;
    const int tid = threadIdx.x;
    const int lane16 = tid & 15;
    const int rgrp = tid >> 4;            // 0..15
    const float* p = pw + (size_t)b * PSTRIDE;
    const float* pb = psum + (size_t)b * 4;
    const float invp = 1.f / (pb[0] + pb[1] + pb[2] + pb[3] + 1e-16f);
    const f32x4 e4 = *(const f32x4*)(p + E_OFF + lane16 * 4);
    const f32x4 a4 = *(const f32x4*)(p + A_OFF + lane16 * 4);
    const float* memb = memory + (size_t)b * RR * CC;
    float* omb = out_mem + (size_t)b * RR * CC;

    #pragma unroll 8
    for (int i = 0; i < 32; ++i) {
        int r = rbase + i * 16 + rgrp;
        float wv = wp[(size_t)b * RR + r] * invp;
        if (lane16 == 0) out_w[(size_t)b * RR + r] = wv;
        f32x4 m4 = *((const f32x4*)(memb + (size_t)r * CC) + lane16);
        f32x4 o;
        o.x = m4.x * (1.f - wv * e4.x) + wv * a4.x;
        o.y = m4.y * (1.f - wv * e4.y) + wv * a4.y;
        o.z = m4.z * (1.f - wv * e4.z) + wv * a4.z;
        o.w = m4.w * (1.f - wv * e4.w) + wv * a4.w;
        __builtin_nontemporal_store(o, (f32x4*)(omb + (size_t)r * CC) + lane16);
    }
}

// ---------------------------------------------------------------------------
// Fallback kernels (small ws): monolithic per-batch weight, then update.
// ---------------------------------------------------------------------------
__global__ __launch_bounds__(256) void weight_kernel_fb(
    const float* __restrict__ sc, const float* __restrict__ prev_w,
    const float* __restrict__ pw, float* __restrict__ out_w)
{
    __shared__ float buf[RR];
    __shared__ float wg[RR];
    __shared__ float red[4];
    const int b = blockIdx.x;
    const int tid = threadIdx.x;
    const float* p = pw + (size_t)b * PSTRIDE;
    const float g = p[G_OFF];
    const float gamma = p[GAMMA_OFF];
    const float s0 = p[S_OFF + 0], s1 = p[S_OFF + 1], s2 = p[S_OFF + 2],
                s3 = p[S_OFF + 3], s4 = p[S_OFF + 4], s5 = p[S_OFF + 5],
                s6 = p[S_OFF + 6];

    float ls = 0.f;
    for (int r = tid; r < RR; r += 256) {
        float ev = sc[(size_t)b * RR + r];
        buf[r] = ev;
        ls += ev;
    }
    const float se = block_reduce_sum4(ls, red);
    const float invse = 1.f / se;
    for (int r = tid; r < RR; r += 256)
        wg[r] = g * (buf[r] * invse) + (1.f - g) * prev_w[(size_t)b * RR + r];
    __syncthreads();
    float lp = 0.f;
    for (int r = tid; r < RR; r += 256) {
        float acc = s0 * wg[(r - 3) & (RR - 1)] + s1 * wg[(r - 2) & (RR - 1)]
                  + s2 * wg[(r - 1) & (RR - 1)] + s3 * wg[r]
                  + s4 * wg[(r + 1) & (RR - 1)] + s5 * wg[(r + 2) & (RR - 1)]
                  + s6 * wg[(r + 3) & (RR - 1)];
        float v = __powf(acc, gamma);
        buf[r] = v;
        lp += v;
    }
    const float ps = block_reduce_sum4(lp, red);
    const float invp = 1.f / (ps + 1e-16f);
    for (int r = tid; r < RR; r += 256)
        out_w[(size_t)b * RR + r] = buf[r] * invp;
}

__global__ __launch_bounds__(256) void update_kernel_fb(
    const float* __restrict__ memory, const float* __restrict__ w,
    const float* __restrict__ pw, float* __restrict__ out_mem)
{
    const int bid = (int)gridDim.x - 1 - (int)blockIdx.x;
    const int b = bid >> 2;
    const int rbase = (bid & 3) * 512;
    const int tid = threadIdx.x;
    const int lane16 = tid & 15;
    const int rgrp = tid >> 4;
    const float* p = pw + (size_t)b * PSTRIDE;
    const f32x4 e4 = *(const f32x4*)(p + E_OFF + lane16 * 4);
    const f32x4 a4 = *(const f32x4*)(p + A_OFF + lane16 * 4);
    const float* memb = memory + (size_t)b * RR * CC;
    float* omb = out_mem + (size_t)b * RR * CC;
    const float* wb = w + (size_t)b * RR;

    #pragma unroll 8
    for (int i = 0; i < 32; ++i) {
        int r = rbase + i * 16 + rgrp;
        float wv = wb[r];
        f32x4 m4 = *((const f32x4*)(memb + (size_t)r * CC) + lane16);
        f32x4 o;
        o.x = m4.x * (1.f - wv * e4.x) + wv * a4.x;
        o.y = m4.y * (1.f - wv * e4.y) + wv * a4.y;
        o.z = m4.z * (1.f - wv * e4.z) + wv * a4.z;
        o.w = m4.w * (1.f - wv * e4.w) + wv * a4.w;
        __builtin_nontemporal_store(o, (f32x4*)(omb + (size_t)r * CC) + lane16);
    }
}

extern "C" void kernel_launch(void* const* d_in, const int* in_sizes, int n_in,
                              void* d_out, int out_size, void* d_ws, size_t ws_size,
                              hipStream_t stream) {
    const float* h      = (const float*)d_in[0];
    const float* prev_w = (const float*)d_in[1];
    const float* memory = (const float*)d_in[2];
    const float* fc_w   = (const float*)d_in[3];
    const float* fc_b   = (const float*)d_in[4];

    float* pw      = (float*)d_ws;              // 512*208 floats
    float* out_w   = (float*)d_out;             // B*R
    float* out_mem = out_w + (size_t)BB * RR;   // B*R*C

    const size_t pw_f   = (size_t)BB * PSTRIDE;
    const size_t br_f   = (size_t)BB * RR;
    const size_t need_f = pw_f + 2 * br_f + 2 * (size_t)BB * 4;

    params_kernel<<<64, 256, 0, stream>>>(h, fc_w, fc_b, pw);

    if (ws_size >= need_f * sizeof(float)) {
        float* sc   = pw + pw_f;
        float* wp   = sc + br_f;
        float* esum = wp + br_f;
        float* psum = esum + (size_t)BB * 4;
        score_kernel<<<BB * 4, 256, 0, stream>>>(memory, pw, sc, esum);
        wconv_kernel<<<BB * 4, 256, 0, stream>>>(sc, prev_w, pw, esum, wp, psum);
        update_kernel<<<BB * 4, 256, 0, stream>>>(memory, wp, psum, pw,
                                                  out_w, out_mem);
    } else {
        // fallback: sc aliased onto out_mem (read fully before overwrite,
        // ordered by kernel boundaries)
        float* sc = out_mem;
        score_kernel<<<BB * 4, 256, 0, stream>>>(memory, pw, sc,
                                                 pw + pw_f /*esum scratch*/);
        weight_kernel_fb<<<BB, 256, 0, stream>>>(sc, prev_w, pw, out_w);
        update_kernel_fb<<<BB * 4, 256, 0, stream>>>(memory, out_w, pw, out_mem);
    }
}